// Round 9
// baseline (356.279 us; speedup 1.0000x reference)
//
#include <hip/hip_runtime.h>
#include <hip/hip_bf16.h>
#include <stdint.h>

#define BB 2
#define SS 2048
#define HH 1024
#define NHH 16
#define HDD 64
#define MM (BB*SS)   // 4096
#define N4SEG (HH*HH/4)   // 262144 = 2^18

typedef __attribute__((ext_vector_type(8))) short short8;
typedef __attribute__((ext_vector_type(4))) float f32x4;
typedef __attribute__((ext_vector_type(4))) unsigned short u16x4;
typedef __attribute__((ext_vector_type(4))) unsigned int u32x4;

__device__ __forceinline__ unsigned short f2bf(float x){
  unsigned u = __float_as_uint(x);
  u += 0x7fffu + ((u >> 16) & 1u);   // RNE; inputs are finite
  return (unsigned short)(u >> 16);
}
__device__ __forceinline__ float bf2f(unsigned short h){
  return __uint_as_float(((unsigned)h) << 16);
}
__device__ __forceinline__ unsigned short f2bf_fast(float x){
  __hip_bfloat16 hb = __float2bfloat16(x);
  return *reinterpret_cast<unsigned short*>(&hb);
}

// ---------------- conversion kernels ----------------
__global__ void k_split(const float* __restrict__ in, unsigned short* __restrict__ hi,
                        unsigned short* __restrict__ lo, int n4){
  int i = blockIdx.x * blockDim.x + threadIdx.x;
  if (i >= n4) return;
  f32x4 x = ((const f32x4*)in)[i];
  u16x4 h, l;
  #pragma unroll
  for (int j = 0; j < 4; ++j){
    unsigned short hb = f2bf(x[j]);
    h[j] = hb;
    l[j] = f2bf(x[j] - bf2f(hb));
  }
  ((u16x4*)hi)[i] = h;
  ((u16x4*)lo)[i] = l;
}

// all 4 weight preps in one launch: seg 0: q(split) 1: k(split) 2: v(plain) 3: o(plain)
__global__ void k_wprep(const float* __restrict__ qs, const float* __restrict__ qd,
                        const float* __restrict__ ks, const float* __restrict__ kd,
                        const float* __restrict__ vs, const float* __restrict__ vd,
                        const float* __restrict__ os_, const float* __restrict__ od,
                        unsigned short* __restrict__ wqh, unsigned short* __restrict__ wql,
                        unsigned short* __restrict__ wkh, unsigned short* __restrict__ wkl,
                        unsigned short* __restrict__ wv,  unsigned short* __restrict__ wo){
  int i = blockIdx.x * blockDim.x + threadIdx.x;
  int seg = i >> 18;
  int j = i & (N4SEG - 1);
  const float *pa, *pb; unsigned short *ph, *pl = nullptr;
  if      (seg == 0){ pa = qs; pb = qd; ph = wqh; pl = wql; }
  else if (seg == 1){ pa = ks; pb = kd; ph = wkh; pl = wkl; }
  else if (seg == 2){ pa = vs; pb = vd; ph = wv; }
  else              { pa = os_; pb = od; ph = wo; }
  f32x4 x = ((const f32x4*)pa)[j] + ((const f32x4*)pb)[j];
  u16x4 h, l;
  #pragma unroll
  for (int c = 0; c < 4; ++c){
    unsigned short hb = f2bf(x[c]);
    h[c] = hb;
    l[c] = f2bf(x[c] - bf2f(hb));
  }
  ((u16x4*)ph)[j] = h;
  if (pl) ((u16x4*)pl)[j] = l;
}

// ---------------- fused QKV projection ----------------
// Default 2-D rasterization (R7 config — R8's manual XCD remap regressed).
// __launch_bounds__(256,3): 768 blocks all co-resident (3/CU) -> no 1.5-round tail.
__global__ __launch_bounds__(256, 3)
void proj_fused(const unsigned short* __restrict__ hsh, const unsigned short* __restrict__ hsl,
                const unsigned short* __restrict__ wqh, const unsigned short* __restrict__ wql,
                const unsigned short* __restrict__ wkh, const unsigned short* __restrict__ wkl,
                const unsigned short* __restrict__ wv,
                unsigned short* __restrict__ qhB, unsigned short* __restrict__ qlB,
                unsigned short* __restrict__ khB, unsigned short* __restrict__ klB,
                unsigned short* __restrict__ vtB)
{
  __shared__ unsigned short Ash[128*32], Asl[128*32], Bsh[128*32], Bsl[128*32];
  const int tid = threadIdx.x;
  const int nb0 = blockIdx.x * 128;        // 0..3071
  const int mb0 = blockIdx.y * 128;
  const int kind = nb0 >> 10;              // 0=q 1=k 2=v
  const int ncol0 = nb0 & 1023;
  const int w  = tid >> 6, lane = tid & 63;
  const int wr = w >> 1,  wc = w & 1;
  const int lg = lane >> 4, lr = lane & 15;

  const unsigned short* Bh = (kind == 0 ? wqh : (kind == 1 ? wkh : wv)) + (size_t)ncol0 * HH;
  const unsigned short* Bl = (kind == 0 ? wql : wkl) + (size_t)ncol0 * HH;  // unused for v
  const unsigned short* Ahb = hsh + (size_t)mb0 * HH;
  const unsigned short* Alb = hsl + (size_t)mb0 * HH;

  f32x4 zero4 = {0.f, 0.f, 0.f, 0.f};
  f32x4 acc[4][4];
  #pragma unroll
  for (int mi = 0; mi < 4; ++mi)
    #pragma unroll
    for (int ni = 0; ni < 4; ++ni) acc[mi][ni] = zero4;

  for (int kb = 0; kb < HH; kb += 32) {
    __syncthreads();
    #pragma unroll
    for (int i = 0; i < 2; ++i){
      int c = i*256 + tid;
      int row = c >> 2, off = (c & 3) << 3;
      size_t go = (size_t)row * HH + kb + off;
      __builtin_amdgcn_global_load_lds(
          (const __attribute__((address_space(1))) void*)(Ahb + go),
          (__attribute__((address_space(3))) void*)(&Ash[c*8]), 16, 0, 0);
      __builtin_amdgcn_global_load_lds(
          (const __attribute__((address_space(1))) void*)(Alb + go),
          (__attribute__((address_space(3))) void*)(&Asl[c*8]), 16, 0, 0);
      __builtin_amdgcn_global_load_lds(
          (const __attribute__((address_space(1))) void*)(Bh + go),
          (__attribute__((address_space(3))) void*)(&Bsh[c*8]), 16, 0, 0);
      if (kind < 2)
        __builtin_amdgcn_global_load_lds(
            (const __attribute__((address_space(1))) void*)(Bl + go),
            (__attribute__((address_space(3))) void*)(&Bsl[c*8]), 16, 0, 0);
    }
    __syncthreads();
    short8 ah4[4], al4[4], bh4[4], bl4[4];
    #pragma unroll
    for (int mi = 0; mi < 4; ++mi){
      int ro = (wr*64 + mi*16 + lr)*32 + lg*8;
      ah4[mi] = *(const short8*)&Ash[ro];
      al4[mi] = *(const short8*)&Asl[ro];
    }
    #pragma unroll
    for (int ni = 0; ni < 4; ++ni){
      int ro = (wc*64 + ni*16 + lr)*32 + lg*8;
      bh4[ni] = *(const short8*)&Bsh[ro];
    }
    if (kind < 2) {
      #pragma unroll
      for (int ni = 0; ni < 4; ++ni){
        int ro = (wc*64 + ni*16 + lr)*32 + lg*8;
        bl4[ni] = *(const short8*)&Bsl[ro];
      }
      #pragma unroll
      for (int mi = 0; mi < 4; ++mi)
        #pragma unroll
        for (int ni = 0; ni < 4; ++ni){
          acc[mi][ni] = __builtin_amdgcn_mfma_f32_16x16x32_bf16(ah4[mi], bh4[ni], acc[mi][ni], 0, 0, 0);
          acc[mi][ni] = __builtin_amdgcn_mfma_f32_16x16x32_bf16(al4[mi], bh4[ni], acc[mi][ni], 0, 0, 0);
          acc[mi][ni] = __builtin_amdgcn_mfma_f32_16x16x32_bf16(ah4[mi], bl4[ni], acc[mi][ni], 0, 0, 0);
        }
    } else {
      #pragma unroll
      for (int mi = 0; mi < 4; ++mi)
        #pragma unroll
        for (int ni = 0; ni < 4; ++ni)
          acc[mi][ni] = __builtin_amdgcn_mfma_f32_16x16x32_bf16(ah4[mi], bh4[ni], acc[mi][ni], 0, 0, 0);
    }
  }

  if (kind == 2) {
    #pragma unroll
    for (int mi = 0; mi < 4; ++mi){
      #pragma unroll
      for (int ni = 0; ni < 4; ++ni){
        int nv = ncol0 + wc*64 + ni*16 + lr;
        int m0 = mb0 + wr*64 + mi*16 + 4*lg;
        int b = m0 >> 11, s0 = m0 & 2047;
        u16x4 pk;
        #pragma unroll
        for (int r = 0; r < 4; ++r) pk[r] = f2bf_fast(acc[mi][ni][r]);
        *(u16x4*)&vtB[((size_t)(b*HH + nv))*SS + s0] = pk;
      }
    }
  } else {
    unsigned short* Ch = (kind == 0) ? qhB : khB;
    unsigned short* Cl = (kind == 0) ? qlB : klB;
    #pragma unroll
    for (int mi = 0; mi < 4; ++mi){
      #pragma unroll
      for (int ni = 0; ni < 4; ++ni){
        int n  = ncol0 + wc*64 + ni*16 + lr;
        int m0 = mb0 + wr*64 + mi*16 + 4*lg;
        #pragma unroll
        for (int r = 0; r < 4; ++r){
          float x = acc[mi][ni][r];
          unsigned short hb = f2bf(x);
          unsigned short lb = f2bf(x - bf2f(hb));
          size_t o = (size_t)(m0 + r)*HH + n;
          Ch[o] = hb;
          Cl[o] = lb;
        }
      }
    }
  }
}

// ---------------- O-projection GEMM (R7 config, no setprio) ----------------
__global__ __launch_bounds__(256, 2)
void gemm_o(const unsigned short* __restrict__ A, const unsigned short* __restrict__ Bm,
            float* __restrict__ C, int M, int N, int K)
{
  __shared__ unsigned short As[128*32];
  __shared__ unsigned short Bs[128*32];
  const int tid = threadIdx.x;
  const int mb0 = blockIdx.y * 128, nb0 = blockIdx.x * 128;
  const int w  = tid >> 6, lane = tid & 63;
  const int wr = w >> 1,  wc = w & 1;
  const int lg = lane >> 4, lr = lane & 15;

  f32x4 zero4 = {0.f, 0.f, 0.f, 0.f};
  f32x4 acc[4][4];
  #pragma unroll
  for (int mi = 0; mi < 4; ++mi)
    #pragma unroll
    for (int ni = 0; ni < 4; ++ni) acc[mi][ni] = zero4;

  const unsigned short* Abase = A  + (size_t)mb0 * K;
  const unsigned short* Bbase = Bm + (size_t)nb0 * K;

  for (int kb = 0; kb < K; kb += 32) {
    __syncthreads();
    #pragma unroll
    for (int i = 0; i < 2; ++i){
      int c = i*256 + tid;
      int row = c >> 2, off = (c & 3) << 3;
      size_t go = (size_t)row * K + kb + off;
      __builtin_amdgcn_global_load_lds(
          (const __attribute__((address_space(1))) void*)(Abase + go),
          (__attribute__((address_space(3))) void*)(&As[c*8]), 16, 0, 0);
      __builtin_amdgcn_global_load_lds(
          (const __attribute__((address_space(1))) void*)(Bbase + go),
          (__attribute__((address_space(3))) void*)(&Bs[c*8]), 16, 0, 0);
    }
    __syncthreads();
    short8 af[4], bfr[4];
    #pragma unroll
    for (int mi = 0; mi < 4; ++mi) af[mi]  = *(const short8*)&As[(wr*64 + mi*16 + lr)*32 + lg*8];
    #pragma unroll
    for (int ni = 0; ni < 4; ++ni) bfr[ni] = *(const short8*)&Bs[(wc*64 + ni*16 + lr)*32 + lg*8];
    #pragma unroll
    for (int mi = 0; mi < 4; ++mi)
      #pragma unroll
      for (int ni = 0; ni < 4; ++ni)
        acc[mi][ni] = __builtin_amdgcn_mfma_f32_16x16x32_bf16(af[mi], bfr[ni], acc[mi][ni], 0, 0, 0);
  }

  #pragma unroll
  for (int mi = 0; mi < 4; ++mi){
    #pragma unroll
    for (int ni = 0; ni < 4; ++ni){
      int n  = nb0 + wc*64 + ni*16 + lr;
      int m0 = mb0 + wr*64 + mi*16 + 4*lg;
      #pragma unroll
      for (int r = 0; r < 4; ++r) C[(size_t)(m0 + r)*N + n] = acc[mi][ni][r];
    }
  }
}

// ---------------- flash attention (v6, unchanged from R8: swapped QK^T,
// in-register P, defer-max T13, setprio T5, paired bf16 packing) ----------------
__global__ __launch_bounds__(512, 4)
void attn_fwd(const unsigned short* __restrict__ qh, const unsigned short* __restrict__ ql,
              const unsigned short* __restrict__ kh, const unsigned short* __restrict__ kl,
              const unsigned short* __restrict__ vt, const float* __restrict__ mask,
              unsigned short* __restrict__ ao)
{
  __shared__ unsigned short Ksh[2][64*64];
  __shared__ unsigned short Ksl[2][64*64];
  __shared__ unsigned short Vss[2][64*64];

  const int tid = threadIdx.x;
  const int w = tid >> 6, lane = tid & 63;
  const int lg = lane >> 4, lr = lane & 15;
  const int xork = (lr & 7) << 4;

  // XCD-aware bijective remap (512 % 8 == 0)
  const int bid = (blockIdx.x & 7) * 64 + (blockIdx.x >> 3);
  const int qb = bid & 15, h = (bid >> 4) & 15, b = bid >> 8;
  const int q0 = qb*128 + w*16;
  const int hoff = h*64;

  const int srow = tid >> 3;
  const int sgx  = (tid & 7) ^ (srow & 7);

  // bpermute byte-addresses (loop-invariant)
  const int aLO = ((lg & 1)*32 + lr) * 4;     // source lane 32*(lg&1)+lr (owns q=lr)
  const int aHI = aLO + 64;                   // source lane +16
  int addr_c[4];
  #pragma unroll
  for (int r = 0; r < 4; ++r) addr_c[r] = (lg*20 + r) * 4;  // lane 16*lg + (4*lg+r)

  short8 qfh[2], qfl[2];
  {
    size_t qoff = ((size_t)(b*SS + q0 + lr))*HH + hoff + lg*8;
    qfh[0] = *(const short8*)(qh + qoff);
    qfl[0] = *(const short8*)(ql + qoff);
    qfh[1] = *(const short8*)(qh + qoff + 32);
    qfl[1] = *(const short8*)(ql + qoff + 32);
  }
  short8 ones8;
  #pragma unroll
  for (int j = 0; j < 8; ++j) ones8[j] = (short)0x3F80;   // bf16 1.0

  float m_run = -1e30f;                       // per lane: running max for q = lr
  f32x4 zero4 = {0.f, 0.f, 0.f, 0.f};
  f32x4 acc[4], acc_l = zero4;
  #pragma unroll
  for (int d4 = 0; d4 < 4; ++d4) acc[d4] = zero4;

  // mask row for q = q0 + lr; per-step dwordx4 at col kv + nb*16 + 4*lg
  const float* mrow = mask + ((size_t)(b*SS + q0 + lr))*SS + 4*lg;

  #define ATTN_STAGE(buf, kvb) do {                                              \
    size_t kro = ((size_t)(b*SS + (kvb) + srow))*HH + hoff + sgx*8;              \
    size_t vro = ((size_t)(b*HH + hoff + srow))*SS + (kvb) + sgx*8;              \
    __builtin_amdgcn_global_load_lds(                                            \
        (const __attribute__((address_space(1))) void*)(kh + kro),               \
        (__attribute__((address_space(3))) void*)(&Ksh[buf][tid*8]), 16, 0, 0);  \
    __builtin_amdgcn_global_load_lds(                                            \
        (const __attribute__((address_space(1))) void*)(kl + kro),               \
        (__attribute__((address_space(3))) void*)(&Ksl[buf][tid*8]), 16, 0, 0);  \
    __builtin_amdgcn_global_load_lds(                                            \
        (const __attribute__((address_space(1))) void*)(vt + vro),               \
        (__attribute__((address_space(3))) void*)(&Vss[buf][tid*8]), 16, 0, 0);  \
  } while (0)

  ATTN_STAGE(0, 0);

  for (int t = 0; t < SS/64; ++t) {
    const int kv = t*64;
    const int cur = t & 1;
    __syncthreads();
    if (t + 1 < SS/64) ATTN_STAGE(cur ^ 1, kv + 64);

    // mask: 4 coalesced dwordx4 from the original layout (lane-local k-slice)
    f32x4 mk[4];
    #pragma unroll
    for (int nb = 0; nb < 4; ++nb) mk[nb] = *(const f32x4*)(mrow + kv + nb*16);

    // QK^T swapped: sc[nb] = C[k-block nb][q=lr]; reg r -> k = kv + 16nb + 4lg + r
    const int c0 = ((0  + lg*16) ^ xork) >> 1;
    const int c1 = ((64 + lg*16) ^ xork) >> 1;
    f32x4 sc[4];
    __builtin_amdgcn_s_setprio(1);
    #pragma unroll
    for (int nb = 0; nb < 4; ++nb) {
      const int krow = (nb*16 + lr)*64;
      short8 k0h = *(const short8*)&Ksh[cur][krow + c0];
      short8 k1h = *(const short8*)&Ksh[cur][krow + c1];
      short8 k0l = *(const short8*)&Ksl[cur][krow + c0];
      short8 k1l = *(const short8*)&Ksl[cur][krow + c1];
      f32x4 d = zero4;
      d = __builtin_amdgcn_mfma_f32_16x16x32_bf16(k0h, qfh[0], d, 0, 0, 0);
      d = __builtin_amdgcn_mfma_f32_16x16x32_bf16(k1h, qfh[1], d, 0, 0, 0);
      d = __builtin_amdgcn_mfma_f32_16x16x32_bf16(k0l, qfh[0], d, 0, 0, 0);
      d = __builtin_amdgcn_mfma_f32_16x16x32_bf16(k1l, qfh[1], d, 0, 0, 0);
      d = __builtin_amdgcn_mfma_f32_16x16x32_bf16(k0h, qfl[0], d, 0, 0, 0);
      d = __builtin_amdgcn_mfma_f32_16x16x32_bf16(k1h, qfl[1], d, 0, 0, 0);
      sc[nb] = d;
    }
    __builtin_amdgcn_s_setprio(0);

    // lane-local scores + row max (16 values for q=lr; combine across lg groups)
    float s[4][4];
    float rmax = -1e30f;
    #pragma unroll
    for (int nb = 0; nb < 4; ++nb)
      #pragma unroll
      for (int r = 0; r < 4; ++r) {
        float v = fmaf(sc[nb][r], 0.125f, mk[nb][r]);
        s[nb][r] = v;
        rmax = fmaxf(rmax, v);
      }
    rmax = fmaxf(rmax, __shfl_xor(rmax, 16));
    rmax = fmaxf(rmax, __shfl_xor(rmax, 32));

    // defer-max (T13, THR=8): skip rescale while max growth is small.
    if (!__all(rmax <= m_run + 8.0f)) {
      float mn = fmaxf(m_run, rmax);
      float corr = __expf(m_run - mn);
      m_run = mn;
      #pragma unroll
      for (int r = 0; r < 4; ++r) {
        float ca = __int_as_float(
            __builtin_amdgcn_ds_bpermute(addr_c[r], __float_as_int(corr)));
        acc_l[r] *= ca;
        #pragma unroll
        for (int d4 = 0; d4 < 4; ++d4) acc[d4][r] *= ca;
      }
    }

    // P = exp(s - m_run) packed to bf16 pairs (compiler pairs the converts)
    unsigned pw[4][2];
    #pragma unroll
    for (int nb = 0; nb < 4; ++nb) {
      float e0 = __expf(s[nb][0] - m_run);
      float e1 = __expf(s[nb][1] - m_run);
      float e2 = __expf(s[nb][2] - m_run);
      float e3 = __expf(s[nb][3] - m_run);
      pw[nb][0] = (unsigned)f2bf_fast(e0) | ((unsigned)f2bf_fast(e1) << 16);
      pw[nb][1] = (unsigned)f2bf_fast(e2) | ((unsigned)f2bf_fast(e3) << 16);
    }

    // gather PV A-fragments: lane (lg,lr) needs P[q=lr][k = 8lg..8lg+7] (pf0)
    // and [32+8lg..] (pf1), from lanes 32(lg&1)+{0,16}+lr, block select lg>>1.
    const int B0 = lg >> 1;
    u32x4 f0, f1;
    {
      unsigned g0 = __builtin_amdgcn_ds_bpermute(aLO, (int)pw[0][0]);
      unsigned g1 = __builtin_amdgcn_ds_bpermute(aLO, (int)pw[0][1]);
      unsigned g2 = __builtin_amdgcn_ds_bpermute(aLO, (int)pw[1][0]);
      unsigned g3 = __builtin_amdgcn_ds_bpermute(aLO, (int)pw[1][1]);
      unsigned g4 = __builtin_amdgcn_ds_bpermute(aHI, (int)pw[0][0]);
      unsigned g5 = __builtin_amdgcn_ds_bpermute(aHI, (int)pw[0][1]);
      unsigned g6 = __builtin_amdgcn_ds_bpermute(aHI, (int)pw[1][0]);
      unsigned g7 = __builtin_amdgcn_ds_bpermute(aHI, (int)pw[1][1]);
      f0[0] = B0 ? g2 : g0;
      f0[1] = B0 ? g3 : g1;
      f0[2] = B0 ? g6 : g4;
      f0[3] = B0 ? g7 : g5;
    }
    {
      unsigned g0 = __builtin_amdgcn_ds_bpermute(aLO, (int)pw[2][0]);
      unsigned g1 = __builtin_amdgcn_ds_bpermute(aLO, (int)pw[2][1]);
      unsigned g2 = __builtin_amdgcn_ds_bpermute(aLO, (int)pw[3][0]);
      unsigned g3 = __builtin_amdgcn_ds_bpermute(aLO, (int)pw[3][1]);
      unsigned g4 = __builtin_amdgcn_ds_bpermute(aHI, (int)pw[2][0]);
      unsigned g5 = __builtin_amdgcn_ds_bpermute(aHI, (int)pw[2][1]);
      unsigned g6 = __builtin_amdgcn_ds_bpermute(aHI, (int)pw[3][0]);
      unsigned g7 = __builtin_amdgcn_ds_bpermute(aHI, (int)pw[3][1]);
      f1[0] = B0 ? g2 : g0;
      f1[1] = B0 ? g3 : g1;
      f1[2] = B0 ? g6 : g4;
      f1[3] = B0 ? g7 : g5;
    }
    short8 pf0 = *reinterpret_cast<short8*>(&f0);
    short8 pf1 = *reinterpret_cast<short8*>(&f1);

    // row sums via MFMA-ones + PV
    __builtin_amdgcn_s_setprio(1);
    acc_l = __builtin_amdgcn_mfma_f32_16x16x32_bf16(pf0, ones8, acc_l, 0, 0, 0);
    acc_l = __builtin_amdgcn_mfma_f32_16x16x32_bf16(pf1, ones8, acc_l, 0, 0, 0);
    #pragma unroll
    for (int d4 = 0; d4 < 4; ++d4) {
      const int vrow = (d4*16 + lr)*64;
      short8 vf0 = *(const short8*)&Vss[cur][vrow + c0];
      short8 vf1 = *(const short8*)&Vss[cur][vrow + c1];
      acc[d4] = __builtin_amdgcn_mfma_f32_16x16x32_bf16(pf0, vf0, acc[d4], 0, 0, 0);
      acc[d4] = __builtin_amdgcn_mfma_f32_16x16x32_bf16(pf1, vf1, acc[d4], 0, 0, 0);
    }
    __builtin_amdgcn_s_setprio(0);
  }
  #undef ATTN_STAGE

  float inv[4];
  #pragma unroll
  for (int r = 0; r < 4; ++r) inv[r] = 1.0f / acc_l[r];
  #pragma unroll
  for (int d4 = 0; d4 < 4; ++d4)
    #pragma unroll
    for (int r = 0; r < 4; ++r) {
      size_t o = ((size_t)(b*SS + q0 + 4*lg + r))*HH + hoff + d4*16 + lr;
      ao[o] = f2bf_fast(acc[d4][r] * inv[r]);
    }
}

// ---------------- launcher ----------------
extern "C" void kernel_launch(void* const* d_in, const int* in_sizes, int n_in,
                              void* d_out, int out_size, void* d_ws, size_t ws_size,
                              hipStream_t stream)
{
  const float* hs  = (const float*)d_in[0];
  const float* msk = (const float*)d_in[1];
  const float* qs  = (const float*)d_in[2];
  const float* qd  = (const float*)d_in[3];
  const float* ks  = (const float*)d_in[4];
  const float* kd  = (const float*)d_in[5];
  const float* vs  = (const float*)d_in[6];
  const float* vd  = (const float*)d_in[7];
  const float* os_ = (const float*)d_in[8];
  const float* od  = (const float*)d_in[9];
  float* out = (float*)d_out;

  const size_t NHS = (size_t)MM * HH;  // 4M elems
  const size_t NW  = (size_t)HH * HH;  // 1M elems
  unsigned short* p = (unsigned short*)d_ws;
  unsigned short* hsh = p; p += NHS;
  unsigned short* hsl = p; p += NHS;
  unsigned short* wqh = p; p += NW;
  unsigned short* wql = p; p += NW;
  unsigned short* wkh = p; p += NW;
  unsigned short* wkl = p; p += NW;
  unsigned short* wv  = p; p += NW;
  unsigned short* wo  = p; p += NW;
  unsigned short* qhB = p; p += NHS;
  unsigned short* qlB = p; p += NHS;
  unsigned short* khB = p; p += NHS;
  unsigned short* klB = p; p += NHS;
  unsigned short* vtB = p; p += NHS;
  unsigned short* aoB = p; p += NHS;
  // total: 38M elems * 2B = 76 MB of d_ws

  k_split<<<(int)(NHS/1024), 256, 0, stream>>>(hs, hsh, hsl, (int)(NHS/4));
  k_wprep<<<(int)(4*N4SEG/256), 256, 0, stream>>>(qs, qd, ks, kd, vs, vd, os_, od,
                                                  wqh, wql, wkh, wkl, wv, wo);

  proj_fused<<<dim3(3*HH/128, MM/128), 256, 0, stream>>>(hsh, hsl, wqh, wql, wkh, wkl, wv,
                                                         qhB, qlB, khB, klB, vtB);

  attn_fwd<<<BB*NHH*(SS/128), 512, 0, stream>>>(qhB, qlB, khB, klB, vtB, msk, aoB);

  gemm_o<<<dim3(HH/128, MM/128), 256, 0, stream>>>(aoB, wo, out, MM, HH, HH);
}

// Round 10
// 336.942 us; speedup vs baseline: 1.0574x; 1.0574x over previous
//
#include <hip/hip_runtime.h>
#include <hip/hip_bf16.h>
#include <stdint.h>

#define BB 2
#define SS 2048
#define HH 1024
#define NHH 16
#define HDD 64
#define MM (BB*SS)   // 4096
#define N4SEG (HH*HH/4)   // 262144 = 2^18

typedef __attribute__((ext_vector_type(8))) short short8;
typedef __attribute__((ext_vector_type(4))) float f32x4;
typedef __attribute__((ext_vector_type(4))) unsigned short u16x4;
typedef __attribute__((ext_vector_type(4))) unsigned int u32x4;

__device__ __forceinline__ unsigned short f2bf(float x){
  unsigned u = __float_as_uint(x);
  u += 0x7fffu + ((u >> 16) & 1u);   // RNE; inputs are finite
  return (unsigned short)(u >> 16);
}
__device__ __forceinline__ float bf2f(unsigned short h){
  return __uint_as_float(((unsigned)h) << 16);
}
__device__ __forceinline__ unsigned short f2bf_fast(float x){
  __hip_bfloat16 hb = __float2bfloat16(x);
  return *reinterpret_cast<unsigned short*>(&hb);
}

// ---------------- conversion kernels ----------------
__global__ void k_split(const float* __restrict__ in, unsigned short* __restrict__ hi,
                        unsigned short* __restrict__ lo, int n4){
  int i = blockIdx.x * blockDim.x + threadIdx.x;
  if (i >= n4) return;
  f32x4 x = ((const f32x4*)in)[i];
  u16x4 h, l;
  #pragma unroll
  for (int j = 0; j < 4; ++j){
    unsigned short hb = f2bf(x[j]);
    h[j] = hb;
    l[j] = f2bf(x[j] - bf2f(hb));
  }
  ((u16x4*)hi)[i] = h;
  ((u16x4*)lo)[i] = l;
}

// all 4 weight preps in one launch: seg 0: q(split) 1: k(split) 2: v(plain) 3: o(plain)
__global__ void k_wprep(const float* __restrict__ qs, const float* __restrict__ qd,
                        const float* __restrict__ ks, const float* __restrict__ kd,
                        const float* __restrict__ vs, const float* __restrict__ vd,
                        const float* __restrict__ os_, const float* __restrict__ od,
                        unsigned short* __restrict__ wqh, unsigned short* __restrict__ wql,
                        unsigned short* __restrict__ wkh, unsigned short* __restrict__ wkl,
                        unsigned short* __restrict__ wv,  unsigned short* __restrict__ wo){
  int i = blockIdx.x * blockDim.x + threadIdx.x;
  int seg = i >> 18;
  int j = i & (N4SEG - 1);
  const float *pa, *pb; unsigned short *ph, *pl = nullptr;
  if      (seg == 0){ pa = qs; pb = qd; ph = wqh; pl = wql; }
  else if (seg == 1){ pa = ks; pb = kd; ph = wkh; pl = wkl; }
  else if (seg == 2){ pa = vs; pb = vd; ph = wv; }
  else              { pa = os_; pb = od; ph = wo; }
  f32x4 x = ((const f32x4*)pa)[j] + ((const f32x4*)pb)[j];
  u16x4 h, l;
  #pragma unroll
  for (int c = 0; c < 4; ++c){
    unsigned short hb = f2bf(x[c]);
    h[c] = hb;
    l[c] = f2bf(x[c] - bf2f(hb));
  }
  ((u16x4*)ph)[j] = h;
  if (pl) ((u16x4*)pl)[j] = l;
}

// ---------------- fused QKV projection ----------------
// R7 config: (256,2), default 2-D raster. v-branch uses SWAPPED MFMA operands so
// the vT epilogue stores are lane-contiguous along s (fixes 5x write amplification
// seen in R9: WRITE_SIZE 200MB for 40MB of data from 4KB-strided 8B stores).
__global__ __launch_bounds__(256, 2)
void proj_fused(const unsigned short* __restrict__ hsh, const unsigned short* __restrict__ hsl,
                const unsigned short* __restrict__ wqh, const unsigned short* __restrict__ wql,
                const unsigned short* __restrict__ wkh, const unsigned short* __restrict__ wkl,
                const unsigned short* __restrict__ wv,
                unsigned short* __restrict__ qhB, unsigned short* __restrict__ qlB,
                unsigned short* __restrict__ khB, unsigned short* __restrict__ klB,
                unsigned short* __restrict__ vtB)
{
  __shared__ unsigned short Ash[128*32], Asl[128*32], Bsh[128*32], Bsl[128*32];
  const int tid = threadIdx.x;
  const int nb0 = blockIdx.x * 128;        // 0..3071
  const int mb0 = blockIdx.y * 128;
  const int kind = nb0 >> 10;              // 0=q 1=k 2=v
  const int ncol0 = nb0 & 1023;
  const int w  = tid >> 6, lane = tid & 63;
  const int wr = w >> 1,  wc = w & 1;
  const int lg = lane >> 4, lr = lane & 15;

  const unsigned short* Bh = (kind == 0 ? wqh : (kind == 1 ? wkh : wv)) + (size_t)ncol0 * HH;
  const unsigned short* Bl = (kind == 0 ? wql : wkl) + (size_t)ncol0 * HH;  // unused for v
  const unsigned short* Ahb = hsh + (size_t)mb0 * HH;
  const unsigned short* Alb = hsl + (size_t)mb0 * HH;

  f32x4 zero4 = {0.f, 0.f, 0.f, 0.f};
  f32x4 acc[4][4];
  #pragma unroll
  for (int mi = 0; mi < 4; ++mi)
    #pragma unroll
    for (int ni = 0; ni < 4; ++ni) acc[mi][ni] = zero4;

  for (int kb = 0; kb < HH; kb += 32) {
    __syncthreads();
    #pragma unroll
    for (int i = 0; i < 2; ++i){
      int c = i*256 + tid;
      int row = c >> 2, off = (c & 3) << 3;
      size_t go = (size_t)row * HH + kb + off;
      __builtin_amdgcn_global_load_lds(
          (const __attribute__((address_space(1))) void*)(Ahb + go),
          (__attribute__((address_space(3))) void*)(&Ash[c*8]), 16, 0, 0);
      __builtin_amdgcn_global_load_lds(
          (const __attribute__((address_space(1))) void*)(Alb + go),
          (__attribute__((address_space(3))) void*)(&Asl[c*8]), 16, 0, 0);
      __builtin_amdgcn_global_load_lds(
          (const __attribute__((address_space(1))) void*)(Bh + go),
          (__attribute__((address_space(3))) void*)(&Bsh[c*8]), 16, 0, 0);
      if (kind < 2)
        __builtin_amdgcn_global_load_lds(
            (const __attribute__((address_space(1))) void*)(Bl + go),
            (__attribute__((address_space(3))) void*)(&Bsl[c*8]), 16, 0, 0);
    }
    __syncthreads();
    short8 ah4[4], al4[4], bh4[4], bl4[4];
    #pragma unroll
    for (int mi = 0; mi < 4; ++mi){
      int ro = (wr*64 + mi*16 + lr)*32 + lg*8;
      ah4[mi] = *(const short8*)&Ash[ro];
      al4[mi] = *(const short8*)&Asl[ro];
    }
    #pragma unroll
    for (int ni = 0; ni < 4; ++ni){
      int ro = (wc*64 + ni*16 + lr)*32 + lg*8;
      bh4[ni] = *(const short8*)&Bsh[ro];
    }
    if (kind < 2) {
      #pragma unroll
      for (int ni = 0; ni < 4; ++ni){
        int ro = (wc*64 + ni*16 + lr)*32 + lg*8;
        bl4[ni] = *(const short8*)&Bsl[ro];
      }
      #pragma unroll
      for (int mi = 0; mi < 4; ++mi)
        #pragma unroll
        for (int ni = 0; ni < 4; ++ni){
          acc[mi][ni] = __builtin_amdgcn_mfma_f32_16x16x32_bf16(ah4[mi], bh4[ni], acc[mi][ni], 0, 0, 0);
          acc[mi][ni] = __builtin_amdgcn_mfma_f32_16x16x32_bf16(al4[mi], bh4[ni], acc[mi][ni], 0, 0, 0);
          acc[mi][ni] = __builtin_amdgcn_mfma_f32_16x16x32_bf16(ah4[mi], bl4[ni], acc[mi][ni], 0, 0, 0);
        }
    } else {
      // swapped operands: C[row = d (wc*64+ni*16+4lg+r), col = s (wr*64+mi*16+lr)]
      #pragma unroll
      for (int mi = 0; mi < 4; ++mi)
        #pragma unroll
        for (int ni = 0; ni < 4; ++ni)
          acc[mi][ni] = __builtin_amdgcn_mfma_f32_16x16x32_bf16(bh4[ni], ah4[mi], acc[mi][ni], 0, 0, 0);
    }
  }

  if (kind == 2) {
    // vT store, lane-contiguous along s: 16 lanes write 32B contiguous per (mi,ni,r)
    #pragma unroll
    for (int mi = 0; mi < 4; ++mi){
      #pragma unroll
      for (int ni = 0; ni < 4; ++ni){
        int d  = ncol0 + wc*64 + ni*16 + 4*lg;     // + r below
        int sg = mb0 + wr*64 + mi*16 + lr;         // global row 0..4095
        int b = sg >> 11, s0 = sg & 2047;
        #pragma unroll
        for (int r = 0; r < 4; ++r)
          vtB[((size_t)(b*HH + d + r))*SS + s0] = f2bf_fast(acc[mi][ni][r]);
      }
    }
  } else {
    unsigned short* Ch = (kind == 0) ? qhB : khB;
    unsigned short* Cl = (kind == 0) ? qlB : klB;
    #pragma unroll
    for (int mi = 0; mi < 4; ++mi){
      #pragma unroll
      for (int ni = 0; ni < 4; ++ni){
        int n  = ncol0 + wc*64 + ni*16 + lr;
        int m0 = mb0 + wr*64 + mi*16 + 4*lg;
        #pragma unroll
        for (int r = 0; r < 4; ++r){
          float x = acc[mi][ni][r];
          unsigned short hb = f2bf(x);
          unsigned short lb = f2bf(x - bf2f(hb));
          size_t o = (size_t)(m0 + r)*HH + n;
          Ch[o] = hb;
          Cl[o] = lb;
        }
      }
    }
  }
}

// ---------------- O-projection GEMM (R7 config) ----------------
__global__ __launch_bounds__(256, 2)
void gemm_o(const unsigned short* __restrict__ A, const unsigned short* __restrict__ Bm,
            float* __restrict__ C, int M, int N, int K)
{
  __shared__ unsigned short As[128*32];
  __shared__ unsigned short Bs[128*32];
  const int tid = threadIdx.x;
  const int mb0 = blockIdx.y * 128, nb0 = blockIdx.x * 128;
  const int w  = tid >> 6, lane = tid & 63;
  const int wr = w >> 1,  wc = w & 1;
  const int lg = lane >> 4, lr = lane & 15;

  f32x4 zero4 = {0.f, 0.f, 0.f, 0.f};
  f32x4 acc[4][4];
  #pragma unroll
  for (int mi = 0; mi < 4; ++mi)
    #pragma unroll
    for (int ni = 0; ni < 4; ++ni) acc[mi][ni] = zero4;

  const unsigned short* Abase = A  + (size_t)mb0 * K;
  const unsigned short* Bbase = Bm + (size_t)nb0 * K;

  for (int kb = 0; kb < K; kb += 32) {
    __syncthreads();
    #pragma unroll
    for (int i = 0; i < 2; ++i){
      int c = i*256 + tid;
      int row = c >> 2, off = (c & 3) << 3;
      size_t go = (size_t)row * K + kb + off;
      __builtin_amdgcn_global_load_lds(
          (const __attribute__((address_space(1))) void*)(Abase + go),
          (__attribute__((address_space(3))) void*)(&As[c*8]), 16, 0, 0);
      __builtin_amdgcn_global_load_lds(
          (const __attribute__((address_space(1))) void*)(Bbase + go),
          (__attribute__((address_space(3))) void*)(&Bs[c*8]), 16, 0, 0);
    }
    __syncthreads();
    short8 af[4], bfr[4];
    #pragma unroll
    for (int mi = 0; mi < 4; ++mi) af[mi]  = *(const short8*)&As[(wr*64 + mi*16 + lr)*32 + lg*8];
    #pragma unroll
    for (int ni = 0; ni < 4; ++ni) bfr[ni] = *(const short8*)&Bs[(wc*64 + ni*16 + lr)*32 + lg*8];
    #pragma unroll
    for (int mi = 0; mi < 4; ++mi)
      #pragma unroll
      for (int ni = 0; ni < 4; ++ni)
        acc[mi][ni] = __builtin_amdgcn_mfma_f32_16x16x32_bf16(af[mi], bfr[ni], acc[mi][ni], 0, 0, 0);
  }

  #pragma unroll
  for (int mi = 0; mi < 4; ++mi){
    #pragma unroll
    for (int ni = 0; ni < 4; ++ni){
      int n  = nb0 + wc*64 + ni*16 + lr;
      int m0 = mb0 + wr*64 + mi*16 + 4*lg;
      #pragma unroll
      for (int r = 0; r < 4; ++r) C[(size_t)(m0 + r)*N + n] = acc[mi][ni][r];
    }
  }
}

// ---------------- flash attention (v7 = v6 + mask double-buffer) ----------------
__global__ __launch_bounds__(512, 4)
void attn_fwd(const unsigned short* __restrict__ qh, const unsigned short* __restrict__ ql,
              const unsigned short* __restrict__ kh, const unsigned short* __restrict__ kl,
              const unsigned short* __restrict__ vt, const float* __restrict__ mask,
              unsigned short* __restrict__ ao)
{
  __shared__ unsigned short Ksh[2][64*64];
  __shared__ unsigned short Ksl[2][64*64];
  __shared__ unsigned short Vss[2][64*64];

  const int tid = threadIdx.x;
  const int w = tid >> 6, lane = tid & 63;
  const int lg = lane >> 4, lr = lane & 15;
  const int xork = (lr & 7) << 4;

  // XCD-aware bijective remap (512 % 8 == 0)
  const int bid = (blockIdx.x & 7) * 64 + (blockIdx.x >> 3);
  const int qb = bid & 15, h = (bid >> 4) & 15, b = bid >> 8;
  const int q0 = qb*128 + w*16;
  const int hoff = h*64;

  const int srow = tid >> 3;
  const int sgx  = (tid & 7) ^ (srow & 7);

  // bpermute byte-addresses (loop-invariant)
  const int aLO = ((lg & 1)*32 + lr) * 4;     // source lane 32*(lg&1)+lr (owns q=lr)
  const int aHI = aLO + 64;                   // source lane +16
  int addr_c[4];
  #pragma unroll
  for (int r = 0; r < 4; ++r) addr_c[r] = (lg*20 + r) * 4;  // lane 16*lg + (4*lg+r)

  short8 qfh[2], qfl[2];
  {
    size_t qoff = ((size_t)(b*SS + q0 + lr))*HH + hoff + lg*8;
    qfh[0] = *(const short8*)(qh + qoff);
    qfl[0] = *(const short8*)(ql + qoff);
    qfh[1] = *(const short8*)(qh + qoff + 32);
    qfl[1] = *(const short8*)(ql + qoff + 32);
  }
  short8 ones8;
  #pragma unroll
  for (int j = 0; j < 8; ++j) ones8[j] = (short)0x3F80;   // bf16 1.0

  float m_run = -1e30f;                       // per lane: running max for q = lr
  f32x4 zero4 = {0.f, 0.f, 0.f, 0.f};
  f32x4 acc[4], acc_l = zero4;
  #pragma unroll
  for (int d4 = 0; d4 < 4; ++d4) acc[d4] = zero4;

  // mask row for q = q0 + lr; per-step dwordx4 at col kv + nb*16 + 4*lg
  const float* mrow = mask + ((size_t)(b*SS + q0 + lr))*SS + 4*lg;

  #define ATTN_STAGE(buf, kvb) do {                                              \
    size_t kro = ((size_t)(b*SS + (kvb) + srow))*HH + hoff + sgx*8;              \
    size_t vro = ((size_t)(b*HH + hoff + srow))*SS + (kvb) + sgx*8;              \
    __builtin_amdgcn_global_load_lds(                                            \
        (const __attribute__((address_space(1))) void*)(kh + kro),               \
        (__attribute__((address_space(3))) void*)(&Ksh[buf][tid*8]), 16, 0, 0);  \
    __builtin_amdgcn_global_load_lds(                                            \
        (const __attribute__((address_space(1))) void*)(kl + kro),               \
        (__attribute__((address_space(3))) void*)(&Ksl[buf][tid*8]), 16, 0, 0);  \
    __builtin_amdgcn_global_load_lds(                                            \
        (const __attribute__((address_space(1))) void*)(vt + vro),               \
        (__attribute__((address_space(3))) void*)(&Vss[buf][tid*8]), 16, 0, 0);  \
  } while (0)

  ATTN_STAGE(0, 0);

  // mask double-buffer: mk = step t's rows (preloaded), mk_n = t+1 (prefetched)
  f32x4 mk[4], mk_n[4];
  #pragma unroll
  for (int nb = 0; nb < 4; ++nb) mk[nb] = *(const f32x4*)(mrow + nb*16);

  for (int t = 0; t < SS/64; ++t) {
    const int kv = t*64;
    const int cur = t & 1;
    __syncthreads();
    if (t + 1 < SS/64) {
      ATTN_STAGE(cur ^ 1, kv + 64);
      #pragma unroll
      for (int nb = 0; nb < 4; ++nb) mk_n[nb] = *(const f32x4*)(mrow + kv + 64 + nb*16);
    }

    // QK^T swapped: sc[nb] = C[k-block nb][q=lr]; reg r -> k = kv + 16nb + 4lg + r
    const int c0 = ((0  + lg*16) ^ xork) >> 1;
    const int c1 = ((64 + lg*16) ^ xork) >> 1;
    f32x4 sc[4];
    __builtin_amdgcn_s_setprio(1);
    #pragma unroll
    for (int nb = 0; nb < 4; ++nb) {
      const int krow = (nb*16 + lr)*64;
      short8 k0h = *(const short8*)&Ksh[cur][krow + c0];
      short8 k1h = *(const short8*)&Ksh[cur][krow + c1];
      short8 k0l = *(const short8*)&Ksl[cur][krow + c0];
      short8 k1l = *(const short8*)&Ksl[cur][krow + c1];
      f32x4 d = zero4;
      d = __builtin_amdgcn_mfma_f32_16x16x32_bf16(k0h, qfh[0], d, 0, 0, 0);
      d = __builtin_amdgcn_mfma_f32_16x16x32_bf16(k1h, qfh[1], d, 0, 0, 0);
      d = __builtin_amdgcn_mfma_f32_16x16x32_bf16(k0l, qfh[0], d, 0, 0, 0);
      d = __builtin_amdgcn_mfma_f32_16x16x32_bf16(k1l, qfh[1], d, 0, 0, 0);
      d = __builtin_amdgcn_mfma_f32_16x16x32_bf16(k0h, qfl[0], d, 0, 0, 0);
      d = __builtin_amdgcn_mfma_f32_16x16x32_bf16(k1h, qfl[1], d, 0, 0, 0);
      sc[nb] = d;
    }
    __builtin_amdgcn_s_setprio(0);

    // lane-local scores + row max (16 values for q=lr; combine across lg groups)
    float s[4][4];
    float rmax = -1e30f;
    #pragma unroll
    for (int nb = 0; nb < 4; ++nb)
      #pragma unroll
      for (int r = 0; r < 4; ++r) {
        float v = fmaf(sc[nb][r], 0.125f, mk[nb][r]);
        s[nb][r] = v;
        rmax = fmaxf(rmax, v);
      }
    rmax = fmaxf(rmax, __shfl_xor(rmax, 16));
    rmax = fmaxf(rmax, __shfl_xor(rmax, 32));

    // defer-max (T13, THR=8): skip rescale while max growth is small.
    if (!__all(rmax <= m_run + 8.0f)) {
      float mn = fmaxf(m_run, rmax);
      float corr = __expf(m_run - mn);
      m_run = mn;
      #pragma unroll
      for (int r = 0; r < 4; ++r) {
        float ca = __int_as_float(
            __builtin_amdgcn_ds_bpermute(addr_c[r], __float_as_int(corr)));
        acc_l[r] *= ca;
        #pragma unroll
        for (int d4 = 0; d4 < 4; ++d4) acc[d4][r] *= ca;
      }
    }

    // P = exp(s - m_run) packed to bf16 pairs (compiler pairs the converts)
    unsigned pw[4][2];
    #pragma unroll
    for (int nb = 0; nb < 4; ++nb) {
      float e0 = __expf(s[nb][0] - m_run);
      float e1 = __expf(s[nb][1] - m_run);
      float e2 = __expf(s[nb][2] - m_run);
      float e3 = __expf(s[nb][3] - m_run);
      pw[nb][0] = (unsigned)f2bf_fast(e0) | ((unsigned)f2bf_fast(e1) << 16);
      pw[nb][1] = (unsigned)f2bf_fast(e2) | ((unsigned)f2bf_fast(e3) << 16);
    }

    // gather PV A-fragments: lane (lg,lr) needs P[q=lr][k = 8lg..8lg+7] (pf0)
    // and [32+8lg..] (pf1), from lanes 32(lg&1)+{0,16}+lr, block select lg>>1.
    const int B0 = lg >> 1;
    u32x4 f0, f1;
    {
      unsigned g0 = __builtin_amdgcn_ds_bpermute(aLO, (int)pw[0][0]);
      unsigned g1 = __builtin_amdgcn_ds_bpermute(aLO, (int)pw[0][1]);
      unsigned g2 = __builtin_amdgcn_ds_bpermute(aLO, (int)pw[1][0]);
      unsigned g3 = __builtin_amdgcn_ds_bpermute(aLO, (int)pw[1][1]);
      unsigned g4 = __builtin_amdgcn_ds_bpermute(aHI, (int)pw[0][0]);
      unsigned g5 = __builtin_amdgcn_ds_bpermute(aHI, (int)pw[0][1]);
      unsigned g6 = __builtin_amdgcn_ds_bpermute(aHI, (int)pw[1][0]);
      unsigned g7 = __builtin_amdgcn_ds_bpermute(aHI, (int)pw[1][1]);
      f0[0] = B0 ? g2 : g0;
      f0[1] = B0 ? g3 : g1;
      f0[2] = B0 ? g6 : g4;
      f0[3] = B0 ? g7 : g5;
    }
    {
      unsigned g0 = __builtin_amdgcn_ds_bpermute(aLO, (int)pw[2][0]);
      unsigned g1 = __builtin_amdgcn_ds_bpermute(aLO, (int)pw[2][1]);
      unsigned g2 = __builtin_amdgcn_ds_bpermute(aLO, (int)pw[3][0]);
      unsigned g3 = __builtin_amdgcn_ds_bpermute(aLO, (int)pw[3][1]);
      unsigned g4 = __builtin_amdgcn_ds_bpermute(aHI, (int)pw[2][0]);
      unsigned g5 = __builtin_amdgcn_ds_bpermute(aHI, (int)pw[2][1]);
      unsigned g6 = __builtin_amdgcn_ds_bpermute(aHI, (int)pw[3][0]);
      unsigned g7 = __builtin_amdgcn_ds_bpermute(aHI, (int)pw[3][1]);
      f1[0] = B0 ? g2 : g0;
      f1[1] = B0 ? g3 : g1;
      f1[2] = B0 ? g6 : g4;
      f1[3] = B0 ? g7 : g5;
    }
    short8 pf0 = *reinterpret_cast<short8*>(&f0);
    short8 pf1 = *reinterpret_cast<short8*>(&f1);

    // row sums via MFMA-ones + PV
    __builtin_amdgcn_s_setprio(1);
    acc_l = __builtin_amdgcn_mfma_f32_16x16x32_bf16(pf0, ones8, acc_l, 0, 0, 0);
    acc_l = __builtin_amdgcn_mfma_f32_16x16x32_bf16(pf1, ones8, acc_l, 0, 0, 0);
    #pragma unroll
    for (int d4 = 0; d4 < 4; ++d4) {
      const int vrow = (d4*16 + lr)*64;
      short8 vf0 = *(const short8*)&Vss[cur][vrow + c0];
      short8 vf1 = *(const short8*)&Vss[cur][vrow + c1];
      acc[d4] = __builtin_amdgcn_mfma_f32_16x16x32_bf16(pf0, vf0, acc[d4], 0, 0, 0);
      acc[d4] = __builtin_amdgcn_mfma_f32_16x16x32_bf16(pf1, vf1, acc[d4], 0, 0, 0);
    }
    __builtin_amdgcn_s_setprio(0);

    #pragma unroll
    for (int nb = 0; nb < 4; ++nb) mk[nb] = mk_n[nb];
  }
  #undef ATTN_STAGE

  float inv[4];
  #pragma unroll
  for (int r = 0; r < 4; ++r) inv[r] = 1.0f / acc_l[r];
  #pragma unroll
  for (int d4 = 0; d4 < 4; ++d4)
    #pragma unroll
    for (int r = 0; r < 4; ++r) {
      size_t o = ((size_t)(b*SS + q0 + 4*lg + r))*HH + hoff + d4*16 + lr;
      ao[o] = f2bf_fast(acc[d4][r] * inv[r]);
    }
}

// ---------------- launcher ----------------
extern "C" void kernel_launch(void* const* d_in, const int* in_sizes, int n_in,
                              void* d_out, int out_size, void* d_ws, size_t ws_size,
                              hipStream_t stream)
{
  const float* hs  = (const float*)d_in[0];
  const float* msk = (const float*)d_in[1];
  const float* qs  = (const float*)d_in[2];
  const float* qd  = (const float*)d_in[3];
  const float* ks  = (const float*)d_in[4];
  const float* kd  = (const float*)d_in[5];
  const float* vs  = (const float*)d_in[6];
  const float* vd  = (const float*)d_in[7];
  const float* os_ = (const float*)d_in[8];
  const float* od  = (const float*)d_in[9];
  float* out = (float*)d_out;

  const size_t NHS = (size_t)MM * HH;  // 4M elems
  const size_t NW  = (size_t)HH * HH;  // 1M elems
  unsigned short* p = (unsigned short*)d_ws;
  unsigned short* hsh = p; p += NHS;
  unsigned short* hsl = p; p += NHS;
  unsigned short* wqh = p; p += NW;
  unsigned short* wql = p; p += NW;
  unsigned short* wkh = p; p += NW;
  unsigned short* wkl = p; p += NW;
  unsigned short* wv  = p; p += NW;
  unsigned short* wo  = p; p += NW;
  unsigned short* qhB = p; p += NHS;
  unsigned short* qlB = p; p += NHS;
  unsigned short* khB = p; p += NHS;
  unsigned short* klB = p; p += NHS;
  unsigned short* vtB = p; p += NHS;
  unsigned short* aoB = p; p += NHS;
  // total: 38M elems * 2B = 76 MB of d_ws

  k_split<<<(int)(NHS/1024), 256, 0, stream>>>(hs, hsh, hsl, (int)(NHS/4));
  k_wprep<<<(int)(4*N4SEG/256), 256, 0, stream>>>(qs, qd, ks, kd, vs, vd, os_, od,
                                                  wqh, wql, wkh, wkl, wv, wo);

  proj_fused<<<dim3(3*HH/128, MM/128), 256, 0, stream>>>(hsh, hsl, wqh, wql, wkh, wkl, wv,
                                                         qhB, qlB, khB, klB, vtB);

  attn_fwd<<<BB*NHH*(SS/128), 512, 0, stream>>>(qhB, qlB, khB, klB, vtB, msk, aoB);

  gemm_o<<<dim3(HH/128, MM/128), 256, 0, stream>>>(aoB, wo, out, MM, HH, HH);
}